// Round 4
// baseline (25401.765 us; speedup 1.0000x reference)
//
#include <hip/hip_runtime.h>
#include <hip/hip_bf16.h>
#include <math.h>

#define NB 32      // batch
#define NN 500     // nodes
#define NF 32      // channels

__device__ __forceinline__ float sigf(float x) { return 1.0f / (1.0f + __expf(-x)); }

// h[b,c,n,t] = b_start[c] + sum_ci w_start[c,ci]*padded_x[b,ci,n,t]; pad 7 zeros at front (19)
__global__ void k_start(const float* x, const float* w, const float* bias, float* h) {
  int idx = blockIdx.x * 256 + threadIdx.x;
  const int total = NB * NF * NN * 19;
  if (idx >= total) return;
  int t = idx % 19;
  int n = (idx / 19) % NN;
  int c = (idx / (19 * NN)) % NF;
  int b = idx / (19 * NN * NF);
  float v = bias[c];
  if (t >= 7) {
    int tx = t - 7;
    v += w[c * 2 + 0] * x[((size_t)(b * 2 + 0) * NN + n) * 12 + tx];
    v += w[c * 2 + 1] * x[((size_t)(b * 2 + 1) * NN + n) * 12 + tx];
  }
  h[idx] = v;
}

// skip0[b,c,n] = b_sk0[c] + sum_{ci,k>=7} w_sk0[c,ci,k]*x[b,ci,n,k-7]
__global__ void k_skip0(const float* x, const float* w, const float* bias, float* s0) {
  int idx = blockIdx.x * 256 + threadIdx.x;
  const int total = NB * 64 * NN;
  if (idx >= total) return;
  int n = idx % NN;
  int c = (idx / NN) % 64;
  int b = idx / (NN * 64);
  float v = bias[c];
  for (int ci = 0; ci < 2; ci++)
    for (int k = 7; k < 19; k++)
      v += w[(c * 2 + ci) * 19 + k] * x[((size_t)(b * 2 + ci) * NN + n) * 12 + (k - 7)];
  s0[idx] = v;
}

// fused gated-TCN (k=3,5,7 concat) + fc + relu-add (+optional residual)
// grid (NN, NB), block 256. h: [B,32,N,Ti] -> out: [B,32,N,To]
__global__ __launch_bounds__(256) void k_gtufc(
    const float* __restrict__ h,
    const float* __restrict__ wg3, const float* __restrict__ bg3,
    const float* __restrict__ wg5, const float* __restrict__ bg5,
    const float* __restrict__ wg7, const float* __restrict__ bg7,
    const float* __restrict__ fw, const float* __restrict__ fb,
    const float* __restrict__ res, int offR,
    float* __restrict__ out, int Ti, int To) {
  int n = blockIdx.x, b = blockIdx.y;
  int tid = threadIdx.x;
  int Tcat = 3 * Ti - 12;
  int offH = Ti - To;
  __shared__ float hs[NF][20];
  __shared__ float tc[NF][45];
  for (int l = tid; l < NF * Ti; l += 256) {
    int c = l / Ti, t = l % Ti;
    hs[c][t] = h[((size_t)(b * NF + c) * NN + n) * Ti + t];
  }
  __syncthreads();
  int L0 = Ti - 2, L1 = Ti - 4;
  for (int l = tid; l < NF * Tcat; l += 256) {
    int c = l / Tcat, t = l % Tcat;
    const float *wg, *bg; int k, t0;
    if (t < L0)            { wg = wg3; bg = bg3; k = 3; t0 = t; }
    else if (t < L0 + L1)  { wg = wg5; bg = bg5; k = 5; t0 = t - L0; }
    else                   { wg = wg7; bg = bg7; k = 7; t0 = t - L0 - L1; }
    float y0 = bg[c], y1 = bg[c + 32];
    for (int ci = 0; ci < NF; ci++)
      for (int j = 0; j < k; j++) {
        float xv = hs[ci][t0 + j];
        y0 += wg[(c * NF + ci) * k + j] * xv;
        y1 += wg[((c + 32) * NF + ci) * k + j] * xv;
      }
    tc[c][t] = tanhf(y0) * sigf(y1);
  }
  __syncthreads();
  for (int l = tid; l < NF * To; l += 256) {
    int c = l / To, o = l % To;
    float acc = fb[o];
    for (int a = 0; a < Tcat; a++) acc += tc[c][a] * fw[o * Tcat + a];
    float v = fmaxf(hs[c][offH + o] + acc, 0.f);
    if (res) v += res[((size_t)(b * NF + c) * NN + n) * Ti + offR + o];
    out[((size_t)(b * NF + c) * NN + n) * To + o] = v;
  }
}

// skip conv (32->64 ch, kernel K) + previous skip (broadcast if prevT==1); out T=7
__global__ void k_skipconv(const float* h, const float* w, const float* bias,
                           const float* prev, int prevT, float* out, int Tin, int K) {
  int total = NB * 64 * NN * 7;
  int idx = blockIdx.x * 256 + threadIdx.x;
  if (idx >= total) return;
  int t = idx % 7;
  int n = (idx / 7) % NN;
  int c = (idx / (7 * NN)) % 64;
  int b = idx / (7 * NN * 64);
  float v = bias[c];
  for (int ci = 0; ci < 32; ci++) {
    const float* hp = h + ((size_t)(b * NF + ci) * NN + n) * Tin + t;
    for (int j = 0; j < K; j++) v += w[(c * 32 + ci) * K + j] * hp[j];
  }
  float pv = (prevT == 1) ? prev[(b * 64 + c) * NN + n] : prev[idx];
  out[idx] = v + pv;
}

// ---- temporal attention ----
__global__ void k_ta_lhs1(const float* h, const float* u1, float* out, int T) {
  int total = NB * T * NF;
  int idx = blockIdx.x * 256 + threadIdx.x;
  if (idx >= total) return;
  int f = idx % NF;
  int t = (idx / NF) % T;
  int b = idx / (NF * T);
  const float* hp = h + ((size_t)(b * NF + f) * NN) * T + t;
  float acc = 0.f;
  for (int n = 0; n < NN; n++) acc += hp[(size_t)n * T] * u1[n];
  out[(b * T + t) * NF + f] = acc;
}
__global__ void k_ta_lhs(const float* l1, const float* u2, float* out, int T) {
  int total = NB * T * NN;
  int idx = blockIdx.x * 256 + threadIdx.x;
  if (idx >= total) return;
  int n = idx % NN;
  int t = (idx / NN) % T;
  int b = idx / (NN * T);
  float acc = 0.f;
  for (int f = 0; f < NF; f++) acc += l1[(b * T + t) * NF + f] * u2[f * NN + n];
  out[idx] = acc;  // (b,t,n)
}
__global__ void k_ta_rhs(const float* h, const float* u3, float* out, int T) {
  int total = NB * NN * T;
  int idx = blockIdx.x * 256 + threadIdx.x;
  if (idx >= total) return;
  int t = idx % T;
  int n = (idx / T) % NN;
  int b = idx / (T * NN);
  float acc = 0.f;
  for (int f = 0; f < NF; f++) acc += u3[f] * h[((size_t)(b * NF + f) * NN + n) * T + t];
  out[idx] = acc;  // (b,n,t)
}
__global__ void k_ta_prod(const float* lhs, const float* rhs, const float* be, float* e0, int T) {
  int total = NB * T * T;
  int idx = blockIdx.x * 256 + threadIdx.x;
  if (idx >= total) return;
  int m = idx % T;
  int t = (idx / T) % T;
  int b = idx / (T * T);
  float acc = 0.f;
  for (int n = 0; n < NN; n++) acc += lhs[(b * T + t) * NN + n] * rhs[(b * NN + n) * T + m];
  e0[idx] = sigf(acc + be[t * T + m]);
}
__global__ void k_ta_e1(const float* e0, const float* ve, float* e1, int T) {
  int total = NB * T * T;
  int idx = blockIdx.x * 256 + threadIdx.x;
  if (idx >= total) return;
  int m = idx % T;
  int t = (idx / T) % T;
  int b = idx / (T * T);
  float acc = 0.f;
  for (int j = 0; j < T; j++) acc += ve[t * T + j] * e0[(b * T + j) * T + m];
  e1[idx] = acc;
}
__global__ void k_ta_smax(const float* e1, float* e, int T) {
  int total = NB * T;
  int idx = blockIdx.x * 256 + threadIdx.x;
  if (idx >= total) return;
  int m = idx % T;
  int b = idx / T;
  float mx = -1e30f;
  for (int t = 0; t < T; t++) mx = fmaxf(mx, e1[(b * T + t) * T + m]);
  float s = 0.f;
  for (int t = 0; t < T; t++) s += __expf(e1[(b * T + t) * T + m] - mx);
  float inv = 1.f / s;
  for (int t = 0; t < T; t++) e[(b * T + t) * T + m] = __expf(e1[(b * T + t) * T + m] - mx) * inv;
}
// xt[b,f,n,t] = sum_j e[b,t,j] * h[b,f,n,j]
__global__ void k_xtat(const float* e, const float* h, float* xt, int T) {
  int total = NB * NF * NN * T;
  int idx = blockIdx.x * 256 + threadIdx.x;
  if (idx >= total) return;
  int t = idx % T;
  int n = (idx / T) % NN;
  int f = (idx / (T * NN)) % NF;
  int b = idx / (T * NN * NF);
  const float* hp = h + ((size_t)(b * NF + f) * NN + n) * T;
  float acc = 0.f;
  for (int j = 0; j < T; j++) acc += e[(b * T + t) * T + j] * hp[j];
  xt[idx] = acc;
}

// ---- spatial attention ----
__global__ void k_sa_lhs1(const float* xt, const float* w1, float* out, int T) {
  int total = NB * NN * NF;
  int idx = blockIdx.x * 256 + threadIdx.x;
  if (idx >= total) return;
  int f = idx % NF;
  int n = (idx / NF) % NN;
  int b = idx / (NF * NN);
  const float* xp = xt + ((size_t)(b * NF + f) * NN + n) * T;
  float acc = 0.f;
  for (int t = 0; t < T; t++) acc += xp[t] * w1[t];
  out[(b * NN + n) * NF + f] = acc;
}
__global__ void k_sa_lhs(const float* l1, const float* w2, float* out, int T) {
  int total = NB * NN * T;
  int idx = blockIdx.x * 256 + threadIdx.x;
  if (idx >= total) return;
  int t = idx % T;
  int n = (idx / T) % NN;
  int b = idx / (T * NN);
  float acc = 0.f;
  for (int f = 0; f < NF; f++) acc += l1[(b * NN + n) * NF + f] * w2[f * T + t];
  out[idx] = acc;  // (b,n,t)
}
__global__ void k_sa_rhs(const float* xt, const float* w3, float* out, int T) {
  int total = NB * T * NN;
  int idx = blockIdx.x * 256 + threadIdx.x;
  if (idx >= total) return;
  int n = idx % NN;
  int t = (idx / NN) % T;
  int b = idx / (NN * T);
  float acc = 0.f;
  for (int f = 0; f < NF; f++) acc += w3[f] * xt[((size_t)(b * NF + f) * NN + n) * T + t];
  out[idx] = acc;  // (b,t,n)
}
__global__ void k_sa_prod(const float* lhs, const float* rhs, const float* bs, float* s0, int T) {
  int total = NB * NN * NN;
  int idx = blockIdx.x * 256 + threadIdx.x;
  if (idx >= total) return;
  int m = idx % NN;
  int n = (idx / NN) % NN;
  int b = idx / (NN * NN);
  float acc = 0.f;
  for (int t = 0; t < T; t++)
    acc += lhs[((size_t)b * NN + n) * T + t] * rhs[((size_t)b * T + t) * NN + m];
  s0[idx] = sigf(acc + bs[(size_t)n * NN + m]);
}
// s1[b] = vs @ s0[b]  (500x500x500, tiled)
__global__ __launch_bounds__(256) void k_gemm_vs(const float* vs, const float* s0, float* s1) {
  __shared__ float As[64][17];
  __shared__ float Bs[16][65];
  int b = blockIdx.z;
  int row0 = blockIdx.y * 64, col0 = blockIdx.x * 64;
  int tx = threadIdx.x, ty = threadIdx.y;
  int tid = ty * 16 + tx;
  float acc[4][4] = {};
  const float* S0 = s0 + (size_t)b * NN * NN;
  for (int k0 = 0; k0 < NN; k0 += 16) {
    for (int l = tid; l < 64 * 16; l += 256) {
      int r = l >> 4, kk = l & 15;
      int gi = row0 + r, gk = k0 + kk;
      As[r][kk] = (gi < NN && gk < NN) ? vs[(size_t)gi * NN + gk] : 0.f;
    }
    for (int l = tid; l < 16 * 64; l += 256) {
      int kk = l >> 6, c = l & 63;
      int gk = k0 + kk, gc = col0 + c;
      Bs[kk][c] = (gk < NN && gc < NN) ? S0[(size_t)gk * NN + gc] : 0.f;
    }
    __syncthreads();
    for (int kk = 0; kk < 16; kk++) {
      float a[4], bb[4];
#pragma unroll
      for (int i = 0; i < 4; i++) a[i] = As[ty * 4 + i][kk];
#pragma unroll
      for (int j = 0; j < 4; j++) bb[j] = Bs[kk][tx * 4 + j];
#pragma unroll
      for (int i = 0; i < 4; i++)
#pragma unroll
        for (int j = 0; j < 4; j++) acc[i][j] += a[i] * bb[j];
    }
    __syncthreads();
  }
  float* S1 = s1 + (size_t)b * NN * NN;
  for (int i = 0; i < 4; i++)
    for (int j = 0; j < 4; j++) {
      int gi = row0 + ty * 4 + i, gc = col0 + tx * 4 + j;
      if (gi < NN && gc < NN) S1[(size_t)gi * NN + gc] = acc[i][j];
    }
}
// softmax over rows r (axis=1), stored transposed: st[b,c,r] = softmax_r(s1[b,r,c])
__global__ void k_sa_smaxT(const float* s1, float* st) {
  int total = NB * NN;
  int idx = blockIdx.x * 256 + threadIdx.x;
  if (idx >= total) return;
  int c = idx % NN;
  int b = idx / NN;
  const float* S = s1 + (size_t)b * NN * NN;
  float mx = -1e30f;
  for (int r = 0; r < NN; r++) mx = fmaxf(mx, S[(size_t)r * NN + c]);
  float sum = 0.f;
  for (int r = 0; r < NN; r++) sum += __expf(S[(size_t)r * NN + c] - mx);
  float inv = 1.f / sum;
  float* O = st + ((size_t)b * NN + c) * NN;
  for (int r = 0; r < NN; r++) O[r] = __expf(S[(size_t)r * NN + c] - mx) * inv;
}

// chebT[k,n,m] = cheb[k,m,n]
__global__ void k_chebT(const float* cheb, float* ct) {
  int total = 3 * NN * NN;
  int idx = blockIdx.x * 256 + threadIdx.x;
  if (idx >= total) return;
  int m = idx % NN;
  int n = (idx / NN) % NN;
  int k = idx / (NN * NN);
  ct[idx] = cheb[((size_t)k * NN + m) * NN + n];
}

// out[b,f2,n,t] = relu( sum_k sum_f theta[k,f,f2] * sum_m (chebT[k,n,m]*st[b,n,m]) * h[b,f,m,t] )
__global__ __launch_bounds__(256) void k_cheb(const float* h, const float* st, const float* ct,
                                              const float* theta, float* out, int T) {
  int n = blockIdx.x, b = blockIdx.y;
  int tid = threadIdx.x;
  __shared__ float w[3][NN];
  __shared__ float accS[3][NF][19];
  for (int m = tid; m < NN; m += 256) {
    float sv = st[((size_t)b * NN + n) * NN + m];
    w[0][m] = ct[(0 * NN + n) * NN + m] * sv;
    w[1][m] = ct[(1 * NN + n) * NN + m] * sv;
    w[2][m] = ct[(2 * NN + n) * NN + m] * sv;
  }
  __syncthreads();
  int items = NF * T;
  for (int it = tid; it < items; it += 256) {
    int f = it / T, t = it % T;
    float a0 = 0.f, a1 = 0.f, a2 = 0.f;
    const float* xp = h + ((size_t)(b * NF + f) * NN) * T + t;
    for (int m = 0; m < NN; m++) {
      float x = xp[(size_t)m * T];
      a0 += w[0][m] * x; a1 += w[1][m] * x; a2 += w[2][m] * x;
    }
    accS[0][f][t] = a0; accS[1][f][t] = a1; accS[2][f][t] = a2;
  }
  __syncthreads();
  for (int it = tid; it < items; it += 256) {
    int f2 = it / T, t = it % T;
    float o = 0.f;
    for (int k = 0; k < 3; k++)
      for (int f = 0; f < NF; f++)
        o += accS[k][f][t] * theta[(k * NF + f) * NF + f2];
    out[((size_t)(b * NF + f2) * NN + n) * T + t] = fmaxf(o, 0.f);
  }
}

// ---- layer norm over (C,N,T) per sample ----
__global__ void k_zero(float* p, int n) {
  int i = blockIdx.x * 256 + threadIdx.x;
  if (i < n) p[i] = 0.f;
}
__global__ void k_ln_part(const float* x, float* acc, int M) {
  int b = blockIdx.y;
  const float* xp = x + (size_t)b * M;
  float s1 = 0.f, s2 = 0.f;
  for (int i = blockIdx.x * blockDim.x + threadIdx.x; i < M; i += gridDim.x * blockDim.x) {
    float v = xp[i]; s1 += v; s2 += v * v;
  }
  __shared__ float r1[256], r2[256];
  int tid = threadIdx.x;
  r1[tid] = s1; r2[tid] = s2;
  __syncthreads();
  for (int s = 128; s > 0; s >>= 1) {
    if (tid < s) { r1[tid] += r1[tid + s]; r2[tid] += r2[tid + s]; }
    __syncthreads();
  }
  if (tid == 0) { atomicAdd(&acc[b * 2], r1[0]); atomicAdd(&acc[b * 2 + 1], r2[0]); }
}
__global__ void k_ln_norm(const float* x, const float* acc, const float* wn, const float* bn,
                          float* out, int M) {
  int total = NB * M;
  int idx = blockIdx.x * 256 + threadIdx.x;
  if (idx >= total) return;
  int b = idx / M;
  int i = idx % M;
  float mean = acc[b * 2] / M;
  float var = acc[b * 2 + 1] / M - mean * mean;
  float y = (x[idx] - mean) * rsqrtf(var + 1e-5f);
  out[idx] = y * wn[i] + bn[i];
}

// ---- final head ----
__global__ void k_fin1(const float* h, const float* w, const float* bias, const float* skip,
                       float* out) {
  int total = NB * 64 * NN;
  int idx = blockIdx.x * 256 + threadIdx.x;
  if (idx >= total) return;
  int n = idx % NN;
  int c = (idx / NN) % 64;
  int b = idx / (NN * 64);
  float v = bias[c];
  for (int ci = 0; ci < 32; ci++) v += w[c * 32 + ci] * h[(b * NF + ci) * NN + n];
  v += skip[((size_t)(b * 64 + c) * NN + n) * 7 + 6];
  out[idx] = fmaxf(v, 0.f);
}
__global__ void k_fin2(const float* in, const float* w, const float* bias, float* out) {
  int total = NB * 128 * NN;
  int idx = blockIdx.x * 256 + threadIdx.x;
  if (idx >= total) return;
  int n = idx % NN;
  int c = (idx / NN) % 128;
  int b = idx / (NN * 128);
  float v = bias[c];
  for (int ci = 0; ci < 64; ci++) v += w[c * 64 + ci] * in[(b * 64 + ci) * NN + n];
  out[idx] = fmaxf(v, 0.f);
}
__global__ void k_fin3(const float* in, const float* w, const float* bias, float* out) {
  int total = NB * 12 * NN;
  int idx = blockIdx.x * 256 + threadIdx.x;
  if (idx >= total) return;
  int n = idx % NN;
  int c = (idx / NN) % 12;
  int b = idx / (NN * 12);
  float v = bias[c];
  for (int ci = 0; ci < 128; ci++) v += w[c * 128 + ci] * in[(b * 128 + ci) * NN + n];
  out[idx] = v;
}

#define G1(tot) dim3((unsigned)(((tot) + 255) / 256)), dim3(256), 0, stream

extern "C" void kernel_launch(void* const* d_in, const int* in_sizes, int n_in,
                              void* d_out, int out_size, void* d_ws, size_t ws_size,
                              hipStream_t stream) {
  (void)in_sizes; (void)n_in; (void)out_size; (void)ws_size;
  auto I = [&](int i) { return (const float*)d_in[i]; };
  float* W = (float*)d_ws;
  size_t off = 0;
  auto alloc = [&](size_t nel) { float* p = W + off; off += nel; return p; };

  // Total: ~47.9M floats = 192 MB
  float* bufA  = alloc(9728000);   // h / residual [B,32,N,19max]
  float* bufB  = alloc(9728000);   // h after fc1 / after fc2
  float* bufC  = alloc(9728000);   // x_tat -> s1(P2) -> cheb output (disjoint lifetimes)
  float* bufSK = alloc(7168000);   // skip [B,64,N,7]
  float* skip0 = alloc(1024000);   // skip [B,64,N,1]
  float* P1    = alloc(8000000);   // s0 / st; reused for F1/F2 at end
  float* CT    = alloc(750000);    // chebT
  float* TL1   = alloc(19456);
  float* TLH   = alloc(304000);
  float* TRH   = alloc(304000);
  float* TE0   = alloc(11552);
  float* TE1   = alloc(11552);
  float* TE    = alloc(11552);
  float* SL1   = alloc(512000);
  float* SLH   = alloc(304000);
  float* SRH   = alloc(304000);
  float* ACC   = alloc(64);
  float* P2 = bufC;                // [B,500,500] lives in bufC before k_cheb writes it
  float* F1 = P1;                  // [B,64,N] final head, after P1 (st) is dead
  float* F2 = P1 + 1024000;        // [B,128,N]

  k_start<<<G1(NB * NF * NN * 19)>>>(I(0), I(1), I(2), bufA);
  k_skip0<<<G1(NB * 64 * NN)>>>(I(0), I(3), I(4), skip0);
  k_chebT<<<G1(3 * NN * NN)>>>(I(59), CT);

  const int Tin[3] = {19, 13, 7}, Tout[3] = {13, 7, 1}, Ksc[3] = {13, 7, 1};
  for (int i = 0; i < 3; i++) {
    int Ti = Tin[i], To = Tout[i];
    // gated TCN + fc1 + relu-add (fc1 maps Tcat back to Ti)
    k_gtufc<<<dim3(NN, NB), dim3(256), 0, stream>>>(
        bufA, I(5), I(6), I(7), I(8), I(9), I(10),
        I(11 + 2 * i), I(12 + 2 * i), nullptr, 0, bufB, Ti, Ti);
    // skip conv (+ broadcast of T=1 skip0 on first layer)
    k_skipconv<<<G1(NB * 64 * NN * 7)>>>(bufB, I(23 + 2 * i), I(24 + 2 * i),
                                         i == 0 ? skip0 : bufSK, i == 0 ? 1 : 7,
                                         bufSK, Ti, Ksc[i]);
    // temporal attention
    int ba = 29 + i * 10;
    k_ta_lhs1<<<G1(NB * Ti * NF)>>>(bufB, I(ba + 0), TL1, Ti);
    k_ta_lhs<<<G1(NB * Ti * NN)>>>(TL1, I(ba + 1), TLH, Ti);
    k_ta_rhs<<<G1(NB * NN * Ti)>>>(bufB, I(ba + 2), TRH, Ti);
    k_ta_prod<<<G1(NB * Ti * Ti)>>>(TLH, TRH, I(ba + 3), TE0, Ti);
    k_ta_e1<<<G1(NB * Ti * Ti)>>>(TE0, I(ba + 4), TE1, Ti);
    k_ta_smax<<<G1(NB * Ti)>>>(TE1, TE, Ti);
    k_xtat<<<G1(NB * NF * NN * Ti)>>>(TE, bufB, bufC, Ti);  // x_tat into bufC
    // spatial attention
    k_sa_lhs1<<<G1(NB * NN * NF)>>>(bufC, I(ba + 5), SL1, Ti);
    k_sa_lhs<<<G1(NB * NN * Ti)>>>(SL1, I(ba + 6), SLH, Ti);
    k_sa_rhs<<<G1(NB * Ti * NN)>>>(bufC, I(ba + 7), SRH, Ti);
    k_sa_prod<<<G1(NB * NN * NN)>>>(SLH, SRH, I(ba + 8), P1, Ti);  // x_tat consumed
    {
      dim3 gg(8, 8, NB), bb(16, 16);
      k_gemm_vs<<<gg, bb, 0, stream>>>(I(ba + 9), P1, P2);  // P2 aliases bufC
    }
    k_sa_smaxT<<<G1(NB * NN)>>>(P2, P1);
    // chebyshev graph conv (reads pre-attention bufB + st(P1), overwrites bufC)
    k_cheb<<<dim3(NN, NB), dim3(256), 0, stream>>>(bufB, P1, CT, I(60), bufC, Ti);
    // second gated TCN + fc2 + relu-add + residual (bufA offset Ti-To)
    k_gtufc<<<dim3(NN, NB), dim3(256), 0, stream>>>(
        bufC, I(5), I(6), I(7), I(8), I(9), I(10),
        I(17 + 2 * i), I(18 + 2 * i), bufA, Ti - To, bufB, Ti, To);
    // layer norm over (C,N,T) per sample: bufB -> bufA
    int M = NF * NN * To;
    k_zero<<<dim3(1), dim3(256), 0, stream>>>(ACC, 64);
    k_ln_part<<<dim3(16, NB), dim3(256), 0, stream>>>(bufB, ACC, M);
    k_ln_norm<<<G1(NB * M)>>>(bufB, ACC, I(61 + 2 * i), I(62 + 2 * i), bufA, M);
  }
  // final head
  k_fin1<<<G1(NB * 64 * NN)>>>(bufA, I(67), I(68), bufSK, F1);
  k_fin2<<<G1(NB * 128 * NN)>>>(F1, I(69), I(70), F2);
  k_fin3<<<G1(NB * 12 * NN)>>>(F2, I(71), I(72), (float*)d_out);
}

// Round 5
// 12116.678 us; speedup vs baseline: 2.0964x; 2.0964x over previous
//
#include <hip/hip_runtime.h>
#include <hip/hip_bf16.h>
#include <math.h>

#define NB 32      // batch
#define NN 500     // nodes
#define NF 32      // channels

__device__ __forceinline__ float sigf(float x) { return 1.0f / (1.0f + __expf(-x)); }

// h[b,c,n,t] = b_start[c] + sum_ci w_start[c,ci]*padded_x[b,ci,n,t]; pad 7 zeros at front (19)
__global__ void k_start(const float* x, const float* w, const float* bias, float* h) {
  int idx = blockIdx.x * 256 + threadIdx.x;
  const int total = NB * NF * NN * 19;
  if (idx >= total) return;
  int t = idx % 19;
  int n = (idx / 19) % NN;
  int c = (idx / (19 * NN)) % NF;
  int b = idx / (19 * NN * NF);
  float v = bias[c];
  if (t >= 7) {
    int tx = t - 7;
    v += w[c * 2 + 0] * x[((size_t)(b * 2 + 0) * NN + n) * 12 + tx];
    v += w[c * 2 + 1] * x[((size_t)(b * 2 + 1) * NN + n) * 12 + tx];
  }
  h[idx] = v;
}

// skip0[b,c,n] = b_sk0[c] + sum_{ci,k>=7} w_sk0[c,ci,k]*x[b,ci,n,k-7]
__global__ void k_skip0(const float* x, const float* w, const float* bias, float* s0) {
  int idx = blockIdx.x * 256 + threadIdx.x;
  const int total = NB * 64 * NN;
  if (idx >= total) return;
  int n = idx % NN;
  int c = (idx / NN) % 64;
  int b = idx / (NN * 64);
  float v = bias[c];
  for (int ci = 0; ci < 2; ci++)
    for (int k = 7; k < 19; k++)
      v += w[(c * 2 + ci) * 19 + k] * x[((size_t)(b * 2 + ci) * NN + n) * 12 + (k - 7)];
  s0[idx] = v;
}

// ---- fused gated-TCN + fc, register-blocked, 8 nodes per block ----
template<int K, int L, int TP, int TCAT, int TO>
__device__ __forceinline__ void gtu_seg(const float* __restrict__ wseg,
                                        const float* __restrict__ bg,
                                        const float* __restrict__ hbase,
                                        const float* __restrict__ fw,
                                        float (&oacc)[TO], int c, int tbase) {
  float y0[L], y1[L];
#pragma unroll
  for (int t = 0; t < L; t++) { y0[t] = 0.f; y1[t] = 0.f; }
#pragma unroll 2
  for (int ci = 0; ci < NF; ci++) {
    float hrow[L + K - 1];
#pragma unroll
    for (int t = 0; t < L + K - 1; t++) hrow[t] = hbase[ci * TP + t];
    float w0[K], w1[K];
#pragma unroll
    for (int j = 0; j < K; j++) {
      w0[j] = wseg[(c * NF + ci) * K + j];
      w1[j] = wseg[((c + 32) * NF + ci) * K + j];
    }
#pragma unroll
    for (int t = 0; t < L; t++)
#pragma unroll
      for (int j = 0; j < K; j++) {
        y0[t] += w0[j] * hrow[t + j];
        y1[t] += w1[j] * hrow[t + j];
      }
  }
  float b0 = bg[c], b1 = bg[c + 32];
#pragma unroll
  for (int t = 0; t < L; t++) {
    float tcv = tanhf(y0[t] + b0) * sigf(y1[t] + b1);
#pragma unroll
    for (int o = 0; o < TO; o++) oacc[o] += tcv * fw[o * TCAT + tbase + t];
  }
}

template<int TI, int TO>
__global__ __launch_bounds__(256) void k_gtufc_t(
    const float* __restrict__ h,
    const float* __restrict__ wg3, const float* __restrict__ bg3,
    const float* __restrict__ wg5, const float* __restrict__ bg5,
    const float* __restrict__ wg7, const float* __restrict__ bg7,
    const float* __restrict__ fw, const float* __restrict__ fb,
    const float* __restrict__ res, float* __restrict__ out) {
  constexpr int TCAT = 3 * TI - 12;
  constexpr int TP = (TI + 3) & ~3;   // pad row to 16B multiple
  constexpr int OFF = TI - TO;
  const int b = blockIdx.y;
  const int n0 = blockIdx.x * 8;
  const int tid = threadIdx.x;
  const int c = tid & 31, nn = tid >> 5;
  const int n = n0 + nn;
  __shared__ float hs[8 * NF * TP];
  for (int l = tid; l < 8 * NF * TP; l += 256) {
    int t = l % TP;
    int ci = (l / TP) % NF;
    int n2 = l / (TP * NF);
    int gn = n0 + n2;
    hs[l] = (t < TI && gn < NN) ? h[((size_t)(b * NF + ci) * NN + gn) * TI + t] : 0.f;
  }
  __syncthreads();
  const float* hbase = hs + nn * NF * TP;
  float oacc[TO];
#pragma unroll
  for (int o = 0; o < TO; o++) oacc[o] = 0.f;
  gtu_seg<3, TI - 2, TP, TCAT, TO>(wg3, bg3, hbase, fw, oacc, c, 0);
  gtu_seg<5, TI - 4, TP, TCAT, TO>(wg5, bg5, hbase, fw, oacc, c, TI - 2);
  gtu_seg<7, TI - 6, TP, TCAT, TO>(wg7, bg7, hbase, fw, oacc, c, 2 * TI - 6);
  if (n < NN) {
    size_t base = (size_t)(b * NF + c) * NN + n;
#pragma unroll
    for (int o = 0; o < TO; o++) {
      float v = fmaxf(hbase[c * TP + OFF + o] + oacc[o] + fb[o], 0.f);
      if (res) v += res[base * TI + OFF + o];
      out[base * TO + o] = v;
    }
  }
}

// skip conv (32->64 ch, kernel K) + previous skip (broadcast if prevT==1); out T=7
__global__ void k_skipconv(const float* h, const float* w, const float* bias,
                           const float* prev, int prevT, float* out, int Tin, int K) {
  int total = NB * 64 * NN * 7;
  int idx = blockIdx.x * 256 + threadIdx.x;
  if (idx >= total) return;
  int t = idx % 7;
  int n = (idx / 7) % NN;
  int c = (idx / (7 * NN)) % 64;
  int b = idx / (7 * NN * 64);
  float v = bias[c];
  for (int ci = 0; ci < 32; ci++) {
    const float* hp = h + ((size_t)(b * NF + ci) * NN + n) * Tin + t;
    for (int j = 0; j < K; j++) v += w[(c * 32 + ci) * K + j] * hp[j];
  }
  float pv = (prevT == 1) ? prev[(b * 64 + c) * NN + n] : prev[idx];
  out[idx] = v + pv;
}

// ---- temporal attention ----
__global__ void k_ta_lhs1(const float* h, const float* u1, float* out, int T) {
  int total = NB * T * NF;
  int idx = blockIdx.x * 256 + threadIdx.x;
  if (idx >= total) return;
  int f = idx % NF;
  int t = (idx / NF) % T;
  int b = idx / (NF * T);
  const float* hp = h + ((size_t)(b * NF + f) * NN) * T + t;
  float acc = 0.f;
  for (int n = 0; n < NN; n++) acc += hp[(size_t)n * T] * u1[n];
  out[(b * T + t) * NF + f] = acc;
}
__global__ void k_ta_lhs(const float* l1, const float* u2, float* out, int T) {
  int total = NB * T * NN;
  int idx = blockIdx.x * 256 + threadIdx.x;
  if (idx >= total) return;
  int n = idx % NN;
  int t = (idx / NN) % T;
  int b = idx / (NN * T);
  float acc = 0.f;
  for (int f = 0; f < NF; f++) acc += l1[(b * T + t) * NF + f] * u2[f * NN + n];
  out[idx] = acc;  // (b,t,n)
}
__global__ void k_ta_rhs(const float* h, const float* u3, float* out, int T) {
  int total = NB * NN * T;
  int idx = blockIdx.x * 256 + threadIdx.x;
  if (idx >= total) return;
  int t = idx % T;
  int n = (idx / T) % NN;
  int b = idx / (T * NN);
  float acc = 0.f;
  for (int f = 0; f < NF; f++) acc += u3[f] * h[((size_t)(b * NF + f) * NN + n) * T + t];
  out[idx] = acc;  // (b,n,t)
}
__global__ void k_ta_prod(const float* lhs, const float* rhs, const float* be, float* e0, int T) {
  int total = NB * T * T;
  int idx = blockIdx.x * 256 + threadIdx.x;
  if (idx >= total) return;
  int m = idx % T;
  int t = (idx / T) % T;
  int b = idx / (T * T);
  float acc = 0.f;
  for (int n = 0; n < NN; n++) acc += lhs[(b * T + t) * NN + n] * rhs[(b * NN + n) * T + m];
  e0[idx] = sigf(acc + be[t * T + m]);
}
__global__ void k_ta_e1(const float* e0, const float* ve, float* e1, int T) {
  int total = NB * T * T;
  int idx = blockIdx.x * 256 + threadIdx.x;
  if (idx >= total) return;
  int m = idx % T;
  int t = (idx / T) % T;
  int b = idx / (T * T);
  float acc = 0.f;
  for (int j = 0; j < T; j++) acc += ve[t * T + j] * e0[(b * T + j) * T + m];
  e1[idx] = acc;
}
__global__ void k_ta_smax(const float* e1, float* e, int T) {
  int total = NB * T;
  int idx = blockIdx.x * 256 + threadIdx.x;
  if (idx >= total) return;
  int m = idx % T;
  int b = idx / T;
  float mx = -1e30f;
  for (int t = 0; t < T; t++) mx = fmaxf(mx, e1[(b * T + t) * T + m]);
  float s = 0.f;
  for (int t = 0; t < T; t++) s += __expf(e1[(b * T + t) * T + m] - mx);
  float inv = 1.f / s;
  for (int t = 0; t < T; t++) e[(b * T + t) * T + m] = __expf(e1[(b * T + t) * T + m] - mx) * inv;
}
// xt[b,f,n,t] = sum_j e[b,t,j] * h[b,f,n,j]
__global__ void k_xtat(const float* e, const float* h, float* xt, int T) {
  int total = NB * NF * NN * T;
  int idx = blockIdx.x * 256 + threadIdx.x;
  if (idx >= total) return;
  int t = idx % T;
  int n = (idx / T) % NN;
  int f = (idx / (T * NN)) % NF;
  int b = idx / (T * NN * NF);
  const float* hp = h + ((size_t)(b * NF + f) * NN + n) * T;
  float acc = 0.f;
  for (int j = 0; j < T; j++) acc += e[(b * T + t) * T + j] * hp[j];
  xt[idx] = acc;
}

// ---- spatial attention ----
__global__ void k_sa_lhs1(const float* xt, const float* w1, float* out, int T) {
  int total = NB * NN * NF;
  int idx = blockIdx.x * 256 + threadIdx.x;
  if (idx >= total) return;
  int f = idx % NF;
  int n = (idx / NF) % NN;
  int b = idx / (NF * NN);
  const float* xp = xt + ((size_t)(b * NF + f) * NN + n) * T;
  float acc = 0.f;
  for (int t = 0; t < T; t++) acc += xp[t] * w1[t];
  out[(b * NN + n) * NF + f] = acc;
}
__global__ void k_sa_lhs(const float* l1, const float* w2, float* out, int T) {
  int total = NB * NN * T;
  int idx = blockIdx.x * 256 + threadIdx.x;
  if (idx >= total) return;
  int t = idx % T;
  int n = (idx / T) % NN;
  int b = idx / (T * NN);
  float acc = 0.f;
  for (int f = 0; f < NF; f++) acc += l1[(b * NN + n) * NF + f] * w2[f * T + t];
  out[idx] = acc;  // (b,n,t)
}
__global__ void k_sa_rhs(const float* xt, const float* w3, float* out, int T) {
  int total = NB * T * NN;
  int idx = blockIdx.x * 256 + threadIdx.x;
  if (idx >= total) return;
  int n = idx % NN;
  int t = (idx / NN) % T;
  int b = idx / (NN * T);
  float acc = 0.f;
  for (int f = 0; f < NF; f++) acc += w3[f] * xt[((size_t)(b * NF + f) * NN + n) * T + t];
  out[idx] = acc;  // (b,t,n)
}
__global__ void k_sa_prod(const float* lhs, const float* rhs, const float* bs, float* s0, int T) {
  int total = NB * NN * NN;
  int idx = blockIdx.x * 256 + threadIdx.x;
  if (idx >= total) return;
  int m = idx % NN;
  int n = (idx / NN) % NN;
  int b = idx / (NN * NN);
  float acc = 0.f;
  for (int t = 0; t < T; t++)
    acc += lhs[((size_t)b * NN + n) * T + t] * rhs[((size_t)b * T + t) * NN + m];
  s0[idx] = sigf(acc + bs[(size_t)n * NN + m]);
}
// s1T[b,c,r] = (vs @ s0[b])[r,c]  (500x500x500, tiled, TRANSPOSED output)
__global__ __launch_bounds__(256) void k_gemm_vs(const float* vs, const float* s0, float* s1t) {
  __shared__ float As[64][17];
  __shared__ float Bs[16][65];
  int b = blockIdx.z;
  int row0 = blockIdx.y * 64, col0 = blockIdx.x * 64;
  int tx = threadIdx.x, ty = threadIdx.y;
  int tid = ty * 16 + tx;
  float acc[4][4] = {};
  const float* S0 = s0 + (size_t)b * NN * NN;
  for (int k0 = 0; k0 < NN; k0 += 16) {
    for (int l = tid; l < 64 * 16; l += 256) {
      int r = l >> 4, kk = l & 15;
      int gi = row0 + r, gk = k0 + kk;
      As[r][kk] = (gi < NN && gk < NN) ? vs[(size_t)gi * NN + gk] : 0.f;
    }
    for (int l = tid; l < 16 * 64; l += 256) {
      int kk = l >> 6, c = l & 63;
      int gk = k0 + kk, gc = col0 + c;
      Bs[kk][c] = (gk < NN && gc < NN) ? S0[(size_t)gk * NN + gc] : 0.f;
    }
    __syncthreads();
    for (int kk = 0; kk < 16; kk++) {
      float a[4], bb[4];
#pragma unroll
      for (int i = 0; i < 4; i++) a[i] = As[ty * 4 + i][kk];
#pragma unroll
      for (int j = 0; j < 4; j++) bb[j] = Bs[kk][tx * 4 + j];
#pragma unroll
      for (int i = 0; i < 4; i++)
#pragma unroll
        for (int j = 0; j < 4; j++) acc[i][j] += a[i] * bb[j];
    }
    __syncthreads();
  }
  float* S1 = s1t + (size_t)b * NN * NN;
  for (int j = 0; j < 4; j++)
    for (int i = 0; i < 4; i++) {
      int gi = row0 + ty * 4 + i, gc = col0 + tx * 4 + j;
      if (gi < NN && gc < NN) S1[(size_t)gc * NN + gi] = acc[i][j];  // transposed
    }
}
// softmax over r (contiguous now): st[b,c,r] = softmax_r(s1t[b,c,r]); block per (c,b)
__global__ __launch_bounds__(256) void k_sa_smax_row(const float* s1t, float* st) {
  int c = blockIdx.x, b = blockIdx.y;
  int tid = threadIdx.x;
  const float* S = s1t + ((size_t)b * NN + c) * NN;
  float* O = st + ((size_t)b * NN + c) * NN;
  __shared__ float red[256];
  float mx = -1e30f;
  for (int i = tid; i < NN; i += 256) mx = fmaxf(mx, S[i]);
  red[tid] = mx;
  __syncthreads();
  for (int s = 128; s > 0; s >>= 1) {
    if (tid < s) red[tid] = fmaxf(red[tid], red[tid + s]);
    __syncthreads();
  }
  mx = red[0];
  __syncthreads();
  float sum = 0.f;
  for (int i = tid; i < NN; i += 256) sum += __expf(S[i] - mx);
  red[tid] = sum;
  __syncthreads();
  for (int s = 128; s > 0; s >>= 1) {
    if (tid < s) red[tid] += red[tid + s];
    __syncthreads();
  }
  float inv = 1.f / red[0];
  for (int i = tid; i < NN; i += 256) O[i] = __expf(S[i] - mx) * inv;
}

// chebT[k,n,m] = cheb[k,m,n]
__global__ void k_chebT(const float* cheb, float* ct) {
  int total = 3 * NN * NN;
  int idx = blockIdx.x * 256 + threadIdx.x;
  if (idx >= total) return;
  int m = idx % NN;
  int n = (idx / NN) % NN;
  int k = idx / (NN * NN);
  ct[idx] = cheb[((size_t)k * NN + m) * NN + n];
}

// out[b,f2,n,t] = relu( sum_k sum_f theta[k,f,f2] * sum_m (chebT[k,n,m]*st[b,n,m]) * h[b,f,m,t] )
__global__ __launch_bounds__(256) void k_cheb(const float* h, const float* st, const float* ct,
                                              const float* theta, float* out, int T) {
  int n = blockIdx.x, b = blockIdx.y;
  int tid = threadIdx.x;
  __shared__ float w[3][NN];
  __shared__ float accS[3][NF][19];
  for (int m = tid; m < NN; m += 256) {
    float sv = st[((size_t)b * NN + n) * NN + m];
    w[0][m] = ct[(0 * NN + n) * NN + m] * sv;
    w[1][m] = ct[(1 * NN + n) * NN + m] * sv;
    w[2][m] = ct[(2 * NN + n) * NN + m] * sv;
  }
  __syncthreads();
  int items = NF * T;
  for (int it = tid; it < items; it += 256) {
    int f = it / T, t = it % T;
    float a0 = 0.f, a1 = 0.f, a2 = 0.f;
    const float* xp = h + ((size_t)(b * NF + f) * NN) * T + t;
    for (int m = 0; m < NN; m++) {
      float x = xp[(size_t)m * T];
      a0 += w[0][m] * x; a1 += w[1][m] * x; a2 += w[2][m] * x;
    }
    accS[0][f][t] = a0; accS[1][f][t] = a1; accS[2][f][t] = a2;
  }
  __syncthreads();
  for (int it = tid; it < items; it += 256) {
    int f2 = it / T, t = it % T;
    float o = 0.f;
    for (int k = 0; k < 3; k++)
      for (int f = 0; f < NF; f++)
        o += accS[k][f][t] * theta[(k * NF + f) * NF + f2];
    out[((size_t)(b * NF + f2) * NN + n) * T + t] = fmaxf(o, 0.f);
  }
}

// ---- layer norm over (C,N,T) per sample ----
__global__ void k_zero(float* p, int n) {
  int i = blockIdx.x * 256 + threadIdx.x;
  if (i < n) p[i] = 0.f;
}
__global__ void k_ln_part(const float* x, float* acc, int M) {
  int b = blockIdx.y;
  const float* xp = x + (size_t)b * M;
  float s1 = 0.f, s2 = 0.f;
  for (int i = blockIdx.x * blockDim.x + threadIdx.x; i < M; i += gridDim.x * blockDim.x) {
    float v = xp[i]; s1 += v; s2 += v * v;
  }
  __shared__ float r1[256], r2[256];
  int tid = threadIdx.x;
  r1[tid] = s1; r2[tid] = s2;
  __syncthreads();
  for (int s = 128; s > 0; s >>= 1) {
    if (tid < s) { r1[tid] += r1[tid + s]; r2[tid] += r2[tid + s]; }
    __syncthreads();
  }
  if (tid == 0) { atomicAdd(&acc[b * 2], r1[0]); atomicAdd(&acc[b * 2 + 1], r2[0]); }
}
__global__ void k_ln_norm(const float* x, const float* acc, const float* wn, const float* bn,
                          float* out, int M) {
  int total = NB * M;
  int idx = blockIdx.x * 256 + threadIdx.x;
  if (idx >= total) return;
  int b = idx / M;
  int i = idx % M;
  float mean = acc[b * 2] / M;
  float var = acc[b * 2 + 1] / M - mean * mean;
  float y = (x[idx] - mean) * rsqrtf(var + 1e-5f);
  out[idx] = y * wn[i] + bn[i];
}

// ---- final head ----
__global__ void k_fin1(const float* h, const float* w, const float* bias, const float* skip,
                       float* out) {
  int total = NB * 64 * NN;
  int idx = blockIdx.x * 256 + threadIdx.x;
  if (idx >= total) return;
  int n = idx % NN;
  int c = (idx / NN) % 64;
  int b = idx / (NN * 64);
  float v = bias[c];
  for (int ci = 0; ci < 32; ci++) v += w[c * 32 + ci] * h[(b * NF + ci) * NN + n];
  v += skip[((size_t)(b * 64 + c) * NN + n) * 7 + 6];
  out[idx] = fmaxf(v, 0.f);
}
__global__ void k_fin2(const float* in, const float* w, const float* bias, float* out) {
  int total = NB * 128 * NN;
  int idx = blockIdx.x * 256 + threadIdx.x;
  if (idx >= total) return;
  int n = idx % NN;
  int c = (idx / NN) % 128;
  int b = idx / (NN * 128);
  float v = bias[c];
  for (int ci = 0; ci < 64; ci++) v += w[c * 64 + ci] * in[(b * 64 + ci) * NN + n];
  out[idx] = fmaxf(v, 0.f);
}
__global__ void k_fin3(const float* in, const float* w, const float* bias, float* out) {
  int total = NB * 12 * NN;
  int idx = blockIdx.x * 256 + threadIdx.x;
  if (idx >= total) return;
  int n = idx % NN;
  int c = (idx / NN) % 12;
  int b = idx / (NN * 12);
  float v = bias[c];
  for (int ci = 0; ci < 128; ci++) v += w[c * 128 + ci] * in[(b * 128 + ci) * NN + n];
  out[idx] = v;
}

#define G1(tot) dim3((unsigned)(((tot) + 255) / 256)), dim3(256), 0, stream

extern "C" void kernel_launch(void* const* d_in, const int* in_sizes, int n_in,
                              void* d_out, int out_size, void* d_ws, size_t ws_size,
                              hipStream_t stream) {
  (void)in_sizes; (void)n_in; (void)out_size; (void)ws_size;
  auto I = [&](int i) { return (const float*)d_in[i]; };
  float* W = (float*)d_ws;
  size_t off = 0;
  auto alloc = [&](size_t nel) { float* p = W + off; off += nel; return p; };

  float* bufA  = alloc(9728000);   // h / residual [B,32,N,19max]
  float* bufB  = alloc(9728000);   // h after fc1 / after fc2
  float* bufC  = alloc(9728000);   // x_tat -> s1T(P2) -> cheb output (disjoint lifetimes)
  float* bufSK = alloc(7168000);   // skip [B,64,N,7]
  float* skip0 = alloc(1024000);   // skip [B,64,N,1]
  float* P1    = alloc(8000000);   // s0 / st; reused for F1/F2 at end
  float* CT    = alloc(750000);    // chebT
  float* TL1   = alloc(19456);
  float* TLH   = alloc(304000);
  float* TRH   = alloc(304000);
  float* TE0   = alloc(11552);
  float* TE1   = alloc(11552);
  float* TE    = alloc(11552);
  float* SL1   = alloc(512000);
  float* SLH   = alloc(304000);
  float* SRH   = alloc(304000);
  float* ACC   = alloc(64);
  float* P2 = bufC;                // [B,500,500] s1T lives in bufC before k_cheb writes it
  float* F1 = P1;                  // [B,64,N] final head, after P1 (st) is dead
  float* F2 = P1 + 1024000;        // [B,128,N]

  k_start<<<G1(NB * NF * NN * 19)>>>(I(0), I(1), I(2), bufA);
  k_skip0<<<G1(NB * 64 * NN)>>>(I(0), I(3), I(4), skip0);
  k_chebT<<<G1(3 * NN * NN)>>>(I(59), CT);

  dim3 ggt((NN + 7) / 8, NB), bgt(256);
  auto gtufc = [&](int Ti, int To, const float* hin, const float* fw, const float* fb,
                   const float* res, float* o) {
    if (Ti == 19 && To == 19)
      k_gtufc_t<19, 19><<<ggt, bgt, 0, stream>>>(hin, I(5), I(6), I(7), I(8), I(9), I(10), fw, fb, res, o);
    else if (Ti == 19 && To == 13)
      k_gtufc_t<19, 13><<<ggt, bgt, 0, stream>>>(hin, I(5), I(6), I(7), I(8), I(9), I(10), fw, fb, res, o);
    else if (Ti == 13 && To == 13)
      k_gtufc_t<13, 13><<<ggt, bgt, 0, stream>>>(hin, I(5), I(6), I(7), I(8), I(9), I(10), fw, fb, res, o);
    else if (Ti == 13 && To == 7)
      k_gtufc_t<13, 7><<<ggt, bgt, 0, stream>>>(hin, I(5), I(6), I(7), I(8), I(9), I(10), fw, fb, res, o);
    else if (Ti == 7 && To == 7)
      k_gtufc_t<7, 7><<<ggt, bgt, 0, stream>>>(hin, I(5), I(6), I(7), I(8), I(9), I(10), fw, fb, res, o);
    else
      k_gtufc_t<7, 1><<<ggt, bgt, 0, stream>>>(hin, I(5), I(6), I(7), I(8), I(9), I(10), fw, fb, res, o);
  };

  const int Tin[3] = {19, 13, 7}, Tout[3] = {13, 7, 1}, Ksc[3] = {13, 7, 1};
  for (int i = 0; i < 3; i++) {
    int Ti = Tin[i], To = Tout[i];
    // gated TCN + fc1 + relu-add (fc1 maps Tcat back to Ti)
    gtufc(Ti, Ti, bufA, I(11 + 2 * i), I(12 + 2 * i), nullptr, bufB);
    // skip conv (+ broadcast of T=1 skip0 on first layer)
    k_skipconv<<<G1(NB * 64 * NN * 7)>>>(bufB, I(23 + 2 * i), I(24 + 2 * i),
                                         i == 0 ? skip0 : bufSK, i == 0 ? 1 : 7,
                                         bufSK, Ti, Ksc[i]);
    // temporal attention
    int ba = 29 + i * 10;
    k_ta_lhs1<<<G1(NB * Ti * NF)>>>(bufB, I(ba + 0), TL1, Ti);
    k_ta_lhs<<<G1(NB * Ti * NN)>>>(TL1, I(ba + 1), TLH, Ti);
    k_ta_rhs<<<G1(NB * NN * Ti)>>>(bufB, I(ba + 2), TRH, Ti);
    k_ta_prod<<<G1(NB * Ti * Ti)>>>(TLH, TRH, I(ba + 3), TE0, Ti);
    k_ta_e1<<<G1(NB * Ti * Ti)>>>(TE0, I(ba + 4), TE1, Ti);
    k_ta_smax<<<G1(NB * Ti)>>>(TE1, TE, Ti);
    k_xtat<<<G1(NB * NF * NN * Ti)>>>(TE, bufB, bufC, Ti);  // x_tat into bufC
    // spatial attention
    k_sa_lhs1<<<G1(NB * NN * NF)>>>(bufC, I(ba + 5), SL1, Ti);
    k_sa_lhs<<<G1(NB * NN * Ti)>>>(SL1, I(ba + 6), SLH, Ti);
    k_sa_rhs<<<G1(NB * Ti * NN)>>>(bufC, I(ba + 7), SRH, Ti);
    k_sa_prod<<<G1(NB * NN * NN)>>>(SLH, SRH, I(ba + 8), P1, Ti);  // x_tat consumed
    {
      dim3 gg(8, 8, NB), bb(16, 16);
      k_gemm_vs<<<gg, bb, 0, stream>>>(I(ba + 9), P1, P2);  // s1T into bufC
    }
    k_sa_smax_row<<<dim3(NN, NB), dim3(256), 0, stream>>>(P2, P1);
    // chebyshev graph conv (reads pre-attention bufB + st(P1), overwrites bufC)
    k_cheb<<<dim3(NN, NB), dim3(256), 0, stream>>>(bufB, P1, CT, I(60), bufC, Ti);
    // second gated TCN + fc2 + relu-add + residual (bufA offset Ti-To)
    gtufc(Ti, To, bufC, I(17 + 2 * i), I(18 + 2 * i), bufA, bufB);
    // layer norm over (C,N,T) per sample: bufB -> bufA
    int M = NF * NN * To;
    k_zero<<<dim3(1), dim3(256), 0, stream>>>(ACC, 64);
    k_ln_part<<<dim3(16, NB), dim3(256), 0, stream>>>(bufB, ACC, M);
    k_ln_norm<<<G1(NB * M)>>>(bufB, ACC, I(61 + 2 * i), I(62 + 2 * i), bufA, M);
  }
  // final head
  k_fin1<<<G1(NB * 64 * NN)>>>(bufA, I(67), I(68), bufSK, F1);
  k_fin2<<<G1(NB * 128 * NN)>>>(F1, I(69), I(70), F2);
  k_fin3<<<G1(NB * 12 * NN)>>>(F2, I(71), I(72), (float*)d_out);
}